// Round 9
// baseline (306.523 us; speedup 1.0000x reference)
//
#include <hip/hip_runtime.h>

using cf = float2;
typedef __attribute__((ext_vector_type(8))) short short8;
typedef __attribute__((ext_vector_type(4))) float floatx4;

// HW packed f32->bf16 RNE convert: low half = a, high half = b
__device__ inline unsigned pk_bf16(float a, float b) {
  unsigned r;
  asm("v_cvt_pk_bf16_f32 %0, %1, %2" : "=v"(r) : "v"(a), "v"(b));
  return r;
}
__device__ inline cf cmul(cf a, cf b) {
  return make_float2(a.x * b.x - a.y * b.y, a.x * b.y + a.y * b.x);
}
__device__ inline cf cadd(cf a, cf b) { return make_float2(a.x + b.x, a.y + b.y); }
__device__ inline cf csub(cf a, cf b) { return make_float2(a.x - b.x, a.y - b.y); }

// Convert 8 f32 (two float4) to split-bf16 hi/lo uint4 pair.
__device__ inline void split8(float4 f0, float4 f1, uint4* hi, uint4* lo) {
  unsigned h01 = pk_bf16(f0.x, f0.y), h23 = pk_bf16(f0.z, f0.w);
  unsigned h45 = pk_bf16(f1.x, f1.y), h67 = pk_bf16(f1.z, f1.w);
  float l0 = f0.x - __uint_as_float(h01 << 16);
  float l1 = f0.y - __uint_as_float(h01 & 0xFFFF0000u);
  float l2 = f0.z - __uint_as_float(h23 << 16);
  float l3 = f0.w - __uint_as_float(h23 & 0xFFFF0000u);
  float l4 = f1.x - __uint_as_float(h45 << 16);
  float l5 = f1.y - __uint_as_float(h45 & 0xFFFF0000u);
  float l6 = f1.z - __uint_as_float(h67 << 16);
  float l7 = f1.w - __uint_as_float(h67 & 0xFFFF0000u);
  *hi = make_uint4(h01, h23, h45, h67);
  *lo = make_uint4(pk_bf16(l0, l1), pk_bf16(l2, l3),
                   pk_bf16(l4, l5), pk_bf16(l6, l7));
}

// ---------------------------------------------------------------------------
// Direct real DFT-32 (numpy rfft convention):
//   X[k] = sum_d x[d] e^{-2pi i k d/32},  k = 0..16
// ---------------------------------------------------------------------------
__device__ inline void rdft32(const float* x, cf* X) {
  #pragma unroll
  for (int k = 0; k <= 16; k++) {
    float s, c;
    __sincosf(-3.14159265358979f * (float)k / 16.0f, &s, &c);
    float wr = 1.0f, wi = 0.0f;
    float ar = 0.0f, ai = 0.0f;
    #pragma unroll
    for (int d = 0; d < 32; d++) {
      ar += x[d] * wr;
      ai += x[d] * wi;
      float t = wr * c - wi * s;
      wi = wr * s + wi * c;
      wr = t;
    }
    X[k] = make_float2(ar, ai);
  }
}

// Direct inverse (numpy irfft convention: only Re of X[0], X[16] used):
__device__ inline void irdft32(const cf* X, float* x) {
  #pragma unroll
  for (int d = 0; d < 32; d++) {
    float s, c;
    __sincosf(3.14159265358979f * (float)d / 16.0f, &s, &c);
    float ur = c, ui = s;
    float acc = X[0].x + (((d & 1) != 0) ? -X[16].x : X[16].x);
    #pragma unroll
    for (int k = 1; k <= 15; k++) {
      acc += 2.0f * (X[k].x * ur - X[k].y * ui);
      float t = ur * c - ui * s;
      ui = ur * s + ui * c;
      ur = t;
    }
    x[d] = acc * 0.03125f;
  }
}

// ---------------------------------------------------------------------------
// K0: one-shot W pre-convert to split-bf16 (hi/lo), fragment-ordered.
// ---------------------------------------------------------------------------
__global__ __launch_bounds__(256) void wconv(
    const float* __restrict__ Wq, const float* __restrict__ Wk,
    const float* __restrict__ Wv,
    unsigned short* __restrict__ Whi, unsigned short* __restrict__ Wlo)
{
  int g = blockIdx.x * 256 + threadIdx.x;
  int c = g & 31, j = (g >> 5) & 255, z = g >> 13;
  const float* W = (z == 0) ? Wq : (z == 1) ? Wk : Wv;
  const float* s = W + (size_t)j * 256 + c * 8;
  uint4 hi, lo;
  split8(*(const float4*)s, *(const float4*)(s + 4), &hi, &lo);
  size_t base = ((size_t)z * 8192 + c * 256 + j) * 8;
  *(uint4*)&Whi[base] = hi;
  *(uint4*)&Wlo[base] = lo;
}

// ---------------------------------------------------------------------------
// K1: 3 projection GEMMs, tile 64m x 256j, [m][j] output (verified r7).
// launch_bounds(256,3): r8 showed (256,4) forces VGPR 64 + spills (regress).
// K-loop fully unrolled; A-prefetch ping-pong issued at iteration TOP so the
// global load gets a full iteration before the barrier's vmcnt(0) drain.
// ---------------------------------------------------------------------------
__global__ __launch_bounds__(256, 3) void gemm_proj(
    const float* __restrict__ Xq, const float* __restrict__ bq,
    const float* __restrict__ Xk, const float* __restrict__ bk,
    const float* __restrict__ Xv, const float* __restrict__ bv,
    const unsigned short* __restrict__ Whi, const unsigned short* __restrict__ Wlo,
    float* __restrict__ dQm, float* __restrict__ dKm, float* __restrict__ dVm)
{
  const int z = blockIdx.z;
  const float* X = (z == 0) ? Xq : (z == 1) ? Xk : Xv;
  const float* bias = (z == 0) ? bq : (z == 1) ? bk : bv;
  float* dst = (z == 0) ? dQm : (z == 1) ? dKm : dVm;
  const unsigned short* WhiZ = Whi + (size_t)z * 65536;
  const unsigned short* WloZ = Wlo + (size_t)z * 65536;

  __shared__ __align__(16) unsigned short sm[2][4160];

  const int tid = threadIdx.x;
  const int m0 = blockIdx.x * 64;
  const int wave = tid >> 6, lane = tid & 63;
  const int lm = lane & 15, quad = lane >> 4;

  floatx4 acc[4][4] = {};   // [mf][jf]

  const int srow = tid >> 2, sq = tid & 3;
  const int sIdx = (sq * 65 + srow) << 3;
  const float* aSrc = X + (size_t)(m0 + srow) * 256 + sq * 8;

  int bOff[4];
  #pragma unroll
  for (int jf = 0; jf < 4; jf++) {
    int j = wave * 64 + jf * 16 + lm;
    bOff[jf] = ((quad * 256) + j) << 3;
  }

  // prologue: stage chunk 0 into buf 0; load chunk 1 -> xa[1]
  {
    uint4 hi, lo;
    split8(*(const float4*)(aSrc), *(const float4*)(aSrc + 4), &hi, &lo);
    *(uint4*)&sm[0][sIdx] = hi;
    *(uint4*)&sm[0][2080 + sIdx] = lo;
  }
  float4 xa[2][2];            // chunk c lives in xa[c&1]; static after unroll
  xa[1][0] = *(const float4*)(aSrc + 32);
  xa[1][1] = *(const float4*)(aSrc + 36);
  __syncthreads();

  #pragma unroll
  for (int ks = 0; ks < 8; ks++) {
    const int p = ks & 1;

    // 1) A global prefetch (chunk ks+2) issued FIRST -> max issue-to-drain
    if (ks < 6) {
      const float* s = aSrc + (ks + 2) * 32;
      xa[p][0] = *(const float4*)s;
      xa[p][1] = *(const float4*)(s + 4);
    }

    // 2) B fragments for this step (L2-resident)
    short8 bhi[4], blo[4];
    #pragma unroll
    for (int jf = 0; jf < 4; jf++) {
      int off = bOff[jf] + ks * 8192;
      bhi[jf] = *(const short8*)&WhiZ[off];
      blo[jf] = *(const short8*)&WloZ[off];
    }

    // 3) A fragments from LDS buf[p]
    short8 ahi[4], alo[4];
    #pragma unroll
    for (int mf = 0; mf < 4; mf++) {
      int idx = (quad * 65 + mf * 16 + lm) << 3;
      ahi[mf] = *(const short8*)&sm[p][idx];
      alo[mf] = *(const short8*)&sm[p][2080 + idx];
    }

    // 4) stage chunk ks+1 (xa[p^1], loaded last iteration) into buf[p^1]
    if (ks < 7) {
      uint4 hi, lo;
      split8(xa[p ^ 1][0], xa[p ^ 1][1], &hi, &lo);
      *(uint4*)&sm[p ^ 1][sIdx] = hi;
      *(uint4*)&sm[p ^ 1][2080 + sIdx] = lo;
    }

    // 5) MFMA: 4 mf x 4 jf x 3 split-products
    #pragma unroll
    for (int mf = 0; mf < 4; mf++)
      #pragma unroll
      for (int jf = 0; jf < 4; jf++) {
        acc[mf][jf] = __builtin_amdgcn_mfma_f32_16x16x32_bf16(
            ahi[mf], bhi[jf], acc[mf][jf], 0, 0, 0);
        acc[mf][jf] = __builtin_amdgcn_mfma_f32_16x16x32_bf16(
            ahi[mf], blo[jf], acc[mf][jf], 0, 0, 0);
        acc[mf][jf] = __builtin_amdgcn_mfma_f32_16x16x32_bf16(
            alo[mf], bhi[jf], acc[mf][jf], 0, 0, 0);
      }

    __syncthreads();
  }

  #pragma unroll
  for (int mf = 0; mf < 4; mf++)
    #pragma unroll
    for (int jf = 0; jf < 4; jf++) {
      int j = wave * 64 + jf * 16 + lm;
      float bj = bias[j];
      int mb = m0 + mf * 16 + quad * 4;
      #pragma unroll
      for (int r = 0; r < 4; r++)
        dst[(size_t)(mb + r) * 256 + j] = acc[mf][jf][r] + bj;
    }
}

// ---------------------------------------------------------------------------
// K1b: standalone head-dim rDFT-32.  src [32768][256] -> dst spectra columns
// dst[((b*8+h)*17+fd)*4096 + n].  One dispatch per tensor.
// ---------------------------------------------------------------------------
__global__ __launch_bounds__(256) void dfft(
    const float* __restrict__ src, cf* __restrict__ dst)
{
  __shared__ float S[32][257];
  const int nt = blockIdx.x;          // 0..127
  const int b = blockIdx.y;           // 0..7
  const int tid = threadIdx.x;
  const int n0 = nt * 32;
  #pragma unroll
  for (int i = 0; i < 32; i++)
    S[i][tid] = src[((size_t)(b * 4096 + n0 + i)) * 256 + tid];
  __syncthreads();
  const int hh = tid >> 5, row = tid & 31;
  float xd[32];
  #pragma unroll
  for (int d = 0; d < 32; d++) xd[d] = S[row][hh * 32 + d];
  cf Xo[17];
  rdft32(xd, Xo);
  const size_t colbase = ((size_t)(b * 8 + hh) * 17) * 4096 + n0 + row;
  #pragma unroll
  for (int fd = 0; fd < 17; fd++)
    dst[colbase + (size_t)fd * 4096] = Xo[fd];
}

// ---------------------------------------------------------------------------
// Radix-8 DIT FFT over 4096 complex points in LDS (swizzled), 256 threads.
// (verified rounds 0-3, 7, 8)
// ---------------------------------------------------------------------------
#define FFT_LDS 4376   // swz(4095) = 4372

__device__ inline int swz(int i) { return i + (i >> 4) + (i >> 8) + (i >> 9); }
__device__ inline int digrev8(int n) {
  return ((n & 7) << 9) | (((n >> 3) & 7) << 6) | (((n >> 6) & 7) << 3) | ((n >> 9) & 7);
}

template<int SIGN>   // -1 forward, +1 inverse
__device__ inline void fft8_stages(cf* X, int tid)
{
  const float C = 0.70710678118654752f;
  const float sg = (float)SIGN;
  #pragma unroll
  for (int s = 0; s < 4; s++) {
    const int q = 1 << (3 * s);                  // 1, 8, 64, 512
    __syncthreads();
    #pragma unroll
    for (int r = 0; r < 2; r++) {
      int t = tid + r * 256;
      int j = t & (q - 1);
      int base = ((t >> (3 * s)) << (3 * s + 3)) + j;
      cf x[8];
      #pragma unroll
      for (int l = 0; l < 8; l++) x[l] = X[swz(base + l * q)];
      if (s > 0) {
        float a = sg * 6.283185307179586f * (float)j / (float)(8 * q);
        float sn, cs;
        __sincosf(a, &sn, &cs);
        cf w1 = make_float2(cs, sn);
        cf w = w1;
        #pragma unroll
        for (int l = 1; l < 8; l++) {
          x[l] = cmul(x[l], w);
          if (l < 7) w = cmul(w, w1);
        }
      }
      cf u0 = cadd(x[0], x[4]), v0 = csub(x[0], x[4]);
      cf u1 = cadd(x[1], x[5]), v1 = csub(x[1], x[5]);
      cf u2 = cadd(x[2], x[6]), v2 = csub(x[2], x[6]);
      cf u3 = cadd(x[3], x[7]), v3 = csub(x[3], x[7]);
      cf w1v = make_float2(C * (v1.x - sg * v1.y), C * (v1.y + sg * v1.x));
      cf w2v = make_float2(-sg * v2.y, sg * v2.x);
      cf w3v = make_float2(C * (-v3.x - sg * v3.y), C * (sg * v3.x - v3.y));
      cf e0 = cadd(u0, u2), e1 = csub(u0, u2);
      cf o0 = cadd(u1, u3), o1 = csub(u1, u3);
      cf F0 = cadd(e0, o0), F4 = csub(e0, o0);
      cf F2 = make_float2(e1.x - sg * o1.y, e1.y + sg * o1.x);
      cf F6 = make_float2(e1.x + sg * o1.y, e1.y - sg * o1.x);
      cf e0b = cadd(v0, w2v), e1b = csub(v0, w2v);
      cf o0b = cadd(w1v, w3v), o1b = csub(w1v, w3v);
      cf F1 = cadd(e0b, o0b), F5 = csub(e0b, o0b);
      cf F3 = make_float2(e1b.x - sg * o1b.y, e1b.y + sg * o1b.x);
      cf F7 = make_float2(e1b.x + sg * o1b.y, e1b.y - sg * o1b.x);
      X[swz(base + 0 * q)] = F0;
      X[swz(base + 1 * q)] = F1;
      X[swz(base + 2 * q)] = F2;
      X[swz(base + 3 * q)] = F3;
      X[swz(base + 4 * q)] = F4;
      X[swz(base + 5 * q)] = F5;
      X[swz(base + 6 * q)] = F6;
      X[swz(base + 7 * q)] = F7;
    }
  }
  __syncthreads();
}

// ---------------------------------------------------------------------------
// K2: per-column seq-domain conv: FFT(Q col), FFT(K col), multiply (x 1/4096),
// IFFT, in place over Qd. K column prefetched into registers at kernel top
// so its HBM latency hides under Q's FFT.
// ---------------------------------------------------------------------------
__global__ __launch_bounds__(256) void seqconv(
    cf* __restrict__ Qd, const cf* __restrict__ Kd)
{
  __shared__ cf X[FFT_LDS];
  const size_t cb = (size_t)blockIdx.x * 4096;
  const int tid = threadIdx.x;

  // K prefetch (issues 16 loads; consumed after Q's FFT)
  cf kreg[16];
  #pragma unroll
  for (int i = 0; i < 16; i++) kreg[i] = Kd[cb + tid + i * 256];

  #pragma unroll
  for (int i = 0; i < 16; i++) {
    int n = tid + i * 256;
    X[swz(digrev8(n))] = Qd[cb + n];
  }
  fft8_stages<-1>(X, tid);

  cf qs[16];
  #pragma unroll
  for (int i = 0; i < 16; i++) qs[i] = X[swz(tid + i * 256)];
  __syncthreads();

  #pragma unroll
  for (int i = 0; i < 16; i++) {
    int n = tid + i * 256;
    X[swz(digrev8(n))] = kreg[i];
  }
  fft8_stages<-1>(X, tid);

  const float inv = 1.0f / 4096.0f;
  #pragma unroll
  for (int i = 0; i < 16; i++) {
    cf kv = X[swz(tid + i * 256)];
    cf p = cmul(qs[i], kv);
    qs[i] = make_float2(p.x * inv, p.y * inv);
  }
  __syncthreads();

  #pragma unroll
  for (int i = 0; i < 16; i++) {
    int f = tid + i * 256;
    X[swz(digrev8(f))] = qs[i];
  }
  fft8_stages<+1>(X, tid);

  #pragma unroll
  for (int i = 0; i < 16; i++) {
    int n = tid + i * 256;
    Qd[cb + n] = X[swz(n)];
  }
}

// ---------------------------------------------------------------------------
// K3: per-(n,h) irDFT-32 + softmax(d) + value gate + residual + LayerNorm.
// ---------------------------------------------------------------------------
__global__ __launch_bounds__(256) void finalize_kernel(
    const cf* __restrict__ Cd, const float* __restrict__ VL,
    const float* __restrict__ vin, const float* __restrict__ gamma,
    const float* __restrict__ beta, float* __restrict__ out)
{
  __shared__ cf Cs[136][33];
  __shared__ float gs[256], bs[256];
  const int n0 = blockIdx.x * 32;
  const int b = blockIdx.y;
  const int tid = threadIdx.x;
  gs[tid] = gamma[tid];
  bs[tid] = beta[tid];
  #pragma unroll
  for (int i = 0; i < 17; i++) {
    int lin = tid + i * 256;          // 0..4351 = 136 cols x 32 n
    int col = lin >> 5, nl = lin & 31;
    Cs[col][nl] = Cd[((size_t)b * 136 + col) * 4096 + n0 + nl];
  }
  __syncthreads();

  const int h = tid & 7, row = tid >> 3;
  const int n = n0 + row;

  cf Xs[17];
  #pragma unroll
  for (int fd = 0; fd < 17; fd++) Xs[fd] = Cs[h * 17 + fd][row];

  float att[32];
  irdft32(Xs, att);

  float mx = att[0];
  #pragma unroll
  for (int d = 1; d < 32; d++) mx = fmaxf(mx, att[d]);
  float ssum = 0.f;
  #pragma unroll
  for (int d = 0; d < 32; d++) { att[d] = __expf(att[d] - mx); ssum += att[d]; }
  const float rs = 1.0f / ssum;

  const size_t base = ((size_t)b * 4096 + n) * 256 + h * 32;
  float o[32];
  float s1 = 0.f, s2 = 0.f;
  #pragma unroll
  for (int i = 0; i < 8; i++) {
    float4 vl = *(const float4*)(VL + base + i * 4);
    float4 vi = *(const float4*)(vin + base + i * 4);
    float o0 = vl.x * (att[i * 4 + 0] * rs) + vi.x;
    float o1 = vl.y * (att[i * 4 + 1] * rs) + vi.y;
    float o2 = vl.z * (att[i * 4 + 2] * rs) + vi.z;
    float o3 = vl.w * (att[i * 4 + 3] * rs) + vi.w;
    o[i * 4 + 0] = o0; o[i * 4 + 1] = o1; o[i * 4 + 2] = o2; o[i * 4 + 3] = o3;
    s1 += o0 + o1 + o2 + o3;
    s2 += o0 * o0 + o1 * o1 + o2 * o2 + o3 * o3;
  }
  #pragma unroll
  for (int off = 1; off < 8; off <<= 1) {
    s1 += __shfl_xor(s1, off, 64);
    s2 += __shfl_xor(s2, off, 64);
  }
  const float mu = s1 * (1.0f / 256.0f);
  const float var = s2 * (1.0f / 256.0f) - mu * mu;
  const float rstd = rsqrtf(var + 1e-5f);
  #pragma unroll
  for (int i = 0; i < 8; i++) {
    float4 ov;
    ov.x = (o[i * 4 + 0] - mu) * rstd * gs[h * 32 + i * 4 + 0] + bs[h * 32 + i * 4 + 0];
    ov.y = (o[i * 4 + 1] - mu) * rstd * gs[h * 32 + i * 4 + 1] + bs[h * 32 + i * 4 + 1];
    ov.z = (o[i * 4 + 2] - mu) * rstd * gs[h * 32 + i * 4 + 2] + bs[h * 32 + i * 4 + 2];
    ov.w = (o[i * 4 + 3] - mu) * rstd * gs[h * 32 + i * 4 + 3] + bs[h * 32 + i * 4 + 3];
    *(float4*)(out + base + i * 4) = ov;
  }
}

// ---------------------------------------------------------------------------
extern "C" void kernel_launch(void* const* d_in, const int* in_sizes, int n_in,
                              void* d_out, int out_size, void* d_ws, size_t ws_size,
                              hipStream_t stream)
{
  const float* q  = (const float*)d_in[0];
  const float* k  = (const float*)d_in[1];
  const float* v  = (const float*)d_in[2];
  const float* Wq = (const float*)d_in[3];
  const float* bq = (const float*)d_in[4];
  const float* Wk = (const float*)d_in[5];
  const float* bk = (const float*)d_in[6];
  const float* Wv = (const float*)d_in[7];
  const float* bv = (const float*)d_in[8];
  const float* ln_gamma = (const float*)d_in[9];
  const float* ln_beta  = (const float*)d_in[10];
  float* out = (float*)d_out;

  // f32-offset workspace plan (peak ~139MB):
  //   QLm @ 0 (aliased later by Kd) / KLm / VL / Qd / Whi+Wlo
  float* ws = (float*)d_ws;
  float* QLm = ws;
  cf* Kd = (cf*)ws;
  float* KLm = ws + (size_t)8912896;
  float* VL  = ws + (size_t)17301504;
  cf* Qd = (cf*)(ws + (size_t)25690112);
  unsigned short* Whi = (unsigned short*)(ws + (size_t)34603008);
  unsigned short* Wlo = Whi + (size_t)3 * 65536;

  wconv<<<96, 256, 0, stream>>>(Wq, Wk, Wv, Whi, Wlo);

  gemm_proj<<<dim3(512, 1, 3), 256, 0, stream>>>(q, bq, k, bk, v, bv,
                                                 Whi, Wlo, QLm, KLm, VL);

  // ordered: dfft-Q reads QLm before dfft-K's output (Kd) overwrites it
  dfft<<<dim3(128, 8), 256, 0, stream>>>(QLm, Qd);
  dfft<<<dim3(128, 8), 256, 0, stream>>>(KLm, Kd);

  seqconv<<<1088, 256, 0, stream>>>(Qd, Kd);

  finalize_kernel<<<dim3(128, 8), 256, 0, stream>>>(Qd, VL, v, ln_gamma,
                                                    ln_beta, out);
}

// Round 10
// 295.420 us; speedup vs baseline: 1.0376x; 1.0376x over previous
//
#include <hip/hip_runtime.h>

using cf = float2;
typedef __attribute__((ext_vector_type(8))) short short8;
typedef __attribute__((ext_vector_type(4))) float floatx4;

// HW packed f32->bf16 RNE convert: low half = a, high half = b
__device__ inline unsigned pk_bf16(float a, float b) {
  unsigned r;
  asm("v_cvt_pk_bf16_f32 %0, %1, %2" : "=v"(r) : "v"(a), "v"(b));
  return r;
}
__device__ inline cf cmul(cf a, cf b) {
  return make_float2(a.x * b.x - a.y * b.y, a.x * b.y + a.y * b.x);
}
__device__ inline cf cadd(cf a, cf b) { return make_float2(a.x + b.x, a.y + b.y); }
__device__ inline cf csub(cf a, cf b) { return make_float2(a.x - b.x, a.y - b.y); }

// Convert 8 f32 (two float4) to split-bf16 hi/lo uint4 pair.
__device__ inline void split8(float4 f0, float4 f1, uint4* hi, uint4* lo) {
  unsigned h01 = pk_bf16(f0.x, f0.y), h23 = pk_bf16(f0.z, f0.w);
  unsigned h45 = pk_bf16(f1.x, f1.y), h67 = pk_bf16(f1.z, f1.w);
  float l0 = f0.x - __uint_as_float(h01 << 16);
  float l1 = f0.y - __uint_as_float(h01 & 0xFFFF0000u);
  float l2 = f0.z - __uint_as_float(h23 << 16);
  float l3 = f0.w - __uint_as_float(h23 & 0xFFFF0000u);
  float l4 = f1.x - __uint_as_float(h45 << 16);
  float l5 = f1.y - __uint_as_float(h45 & 0xFFFF0000u);
  float l6 = f1.z - __uint_as_float(h67 << 16);
  float l7 = f1.w - __uint_as_float(h67 & 0xFFFF0000u);
  *hi = make_uint4(h01, h23, h45, h67);
  *lo = make_uint4(pk_bf16(l0, l1), pk_bf16(l2, l3),
                   pk_bf16(l4, l5), pk_bf16(l6, l7));
}

// ---------------------------------------------------------------------------
// Direct real DFT-32 (numpy rfft convention).
// ---------------------------------------------------------------------------
__device__ inline void rdft32(const float* x, cf* X) {
  #pragma unroll
  for (int k = 0; k <= 16; k++) {
    float s, c;
    __sincosf(-3.14159265358979f * (float)k / 16.0f, &s, &c);
    float wr = 1.0f, wi = 0.0f;
    float ar = 0.0f, ai = 0.0f;
    #pragma unroll
    for (int d = 0; d < 32; d++) {
      ar += x[d] * wr;
      ai += x[d] * wi;
      float t = wr * c - wi * s;
      wi = wr * s + wi * c;
      wr = t;
    }
    X[k] = make_float2(ar, ai);
  }
}

// Direct inverse (numpy irfft convention: only Re of X[0], X[16] used):
__device__ inline void irdft32(const cf* X, float* x) {
  #pragma unroll
  for (int d = 0; d < 32; d++) {
    float s, c;
    __sincosf(3.14159265358979f * (float)d / 16.0f, &s, &c);
    float ur = c, ui = s;
    float acc = X[0].x + (((d & 1) != 0) ? -X[16].x : X[16].x);
    #pragma unroll
    for (int k = 1; k <= 15; k++) {
      acc += 2.0f * (X[k].x * ur - X[k].y * ui);
      float t = ur * c - ui * s;
      ui = ur * s + ui * c;
      ur = t;
    }
    x[d] = acc * 0.03125f;
  }
}

// ---------------------------------------------------------------------------
// K0: one-shot W pre-convert to split-bf16 (hi/lo), fragment-ordered.
// ---------------------------------------------------------------------------
__global__ __launch_bounds__(256) void wconv(
    const float* __restrict__ Wq, const float* __restrict__ Wk,
    const float* __restrict__ Wv,
    unsigned short* __restrict__ Whi, unsigned short* __restrict__ Wlo)
{
  int g = blockIdx.x * 256 + threadIdx.x;
  int c = g & 31, j = (g >> 5) & 255, z = g >> 13;
  const float* W = (z == 0) ? Wq : (z == 1) ? Wk : Wv;
  const float* s = W + (size_t)j * 256 + c * 8;
  uint4 hi, lo;
  split8(*(const float4*)s, *(const float4*)(s + 4), &hi, &lo);
  size_t base = ((size_t)z * 8192 + c * 256 + j) * 8;
  *(uint4*)&Whi[base] = hi;
  *(uint4*)&Wlo[base] = lo;
}

// ---------------------------------------------------------------------------
// K1: 3 projection GEMMs, tile 64m x 256j, [m][j] output (verified r7).
// ---------------------------------------------------------------------------
__global__ __launch_bounds__(256, 3) void gemm_proj(
    const float* __restrict__ Xq, const float* __restrict__ bq,
    const float* __restrict__ Xk, const float* __restrict__ bk,
    const float* __restrict__ Xv, const float* __restrict__ bv,
    const unsigned short* __restrict__ Whi, const unsigned short* __restrict__ Wlo,
    float* __restrict__ dQm, float* __restrict__ dKm, float* __restrict__ dVm)
{
  const int z = blockIdx.z;
  const float* X = (z == 0) ? Xq : (z == 1) ? Xk : Xv;
  const float* bias = (z == 0) ? bq : (z == 1) ? bk : bv;
  float* dst = (z == 0) ? dQm : (z == 1) ? dKm : dVm;
  const unsigned short* WhiZ = Whi + (size_t)z * 65536;
  const unsigned short* WloZ = Wlo + (size_t)z * 65536;

  __shared__ __align__(16) unsigned short sm[2][4160];

  const int tid = threadIdx.x;
  const int m0 = blockIdx.x * 64;
  const int wave = tid >> 6, lane = tid & 63;
  const int lm = lane & 15, quad = lane >> 4;

  floatx4 acc[4][4] = {};   // [mf][jf]

  const int srow = tid >> 2, sq = tid & 3;
  const int sIdx = (sq * 65 + srow) << 3;
  const float* aSrc = X + (size_t)(m0 + srow) * 256 + sq * 8;

  int bOff[4];
  #pragma unroll
  for (int jf = 0; jf < 4; jf++) {
    int j = wave * 64 + jf * 16 + lm;
    bOff[jf] = ((quad * 256) + j) << 3;
  }

  {
    uint4 hi, lo;
    split8(*(const float4*)(aSrc), *(const float4*)(aSrc + 4), &hi, &lo);
    *(uint4*)&sm[0][sIdx] = hi;
    *(uint4*)&sm[0][2080 + sIdx] = lo;
  }
  float4 xa[2][2];            // chunk c lives in xa[c&1]; static after unroll
  xa[1][0] = *(const float4*)(aSrc + 32);
  xa[1][1] = *(const float4*)(aSrc + 36);
  __syncthreads();

  #pragma unroll
  for (int ks = 0; ks < 8; ks++) {
    const int p = ks & 1;

    if (ks < 6) {
      const float* s = aSrc + (ks + 2) * 32;
      xa[p][0] = *(const float4*)s;
      xa[p][1] = *(const float4*)(s + 4);
    }

    short8 bhi[4], blo[4];
    #pragma unroll
    for (int jf = 0; jf < 4; jf++) {
      int off = bOff[jf] + ks * 8192;
      bhi[jf] = *(const short8*)&WhiZ[off];
      blo[jf] = *(const short8*)&WloZ[off];
    }

    short8 ahi[4], alo[4];
    #pragma unroll
    for (int mf = 0; mf < 4; mf++) {
      int idx = (quad * 65 + mf * 16 + lm) << 3;
      ahi[mf] = *(const short8*)&sm[p][idx];
      alo[mf] = *(const short8*)&sm[p][2080 + idx];
    }

    if (ks < 7) {
      uint4 hi, lo;
      split8(xa[p ^ 1][0], xa[p ^ 1][1], &hi, &lo);
      *(uint4*)&sm[p ^ 1][sIdx] = hi;
      *(uint4*)&sm[p ^ 1][2080 + sIdx] = lo;
    }

    #pragma unroll
    for (int mf = 0; mf < 4; mf++)
      #pragma unroll
      for (int jf = 0; jf < 4; jf++) {
        acc[mf][jf] = __builtin_amdgcn_mfma_f32_16x16x32_bf16(
            ahi[mf], bhi[jf], acc[mf][jf], 0, 0, 0);
        acc[mf][jf] = __builtin_amdgcn_mfma_f32_16x16x32_bf16(
            ahi[mf], blo[jf], acc[mf][jf], 0, 0, 0);
        acc[mf][jf] = __builtin_amdgcn_mfma_f32_16x16x32_bf16(
            alo[mf], bhi[jf], acc[mf][jf], 0, 0, 0);
      }

    __syncthreads();
  }

  #pragma unroll
  for (int mf = 0; mf < 4; mf++)
    #pragma unroll
    for (int jf = 0; jf < 4; jf++) {
      int j = wave * 64 + jf * 16 + lm;
      float bj = bias[j];
      int mb = m0 + mf * 16 + quad * 4;
      #pragma unroll
      for (int r = 0; r < 4; r++)
        dst[(size_t)(mb + r) * 256 + j] = acc[mf][jf][r] + bj;
    }
}

// ---------------------------------------------------------------------------
// K1b: standalone head-dim rDFT-32 (verified r7).
// ---------------------------------------------------------------------------
__global__ __launch_bounds__(256) void dfft(
    const float* __restrict__ src, cf* __restrict__ dst)
{
  __shared__ float S[32][257];
  const int nt = blockIdx.x;          // 0..127
  const int b = blockIdx.y;           // 0..7
  const int tid = threadIdx.x;
  const int n0 = nt * 32;
  #pragma unroll
  for (int i = 0; i < 32; i++)
    S[i][tid] = src[((size_t)(b * 4096 + n0 + i)) * 256 + tid];
  __syncthreads();
  const int hh = tid >> 5, row = tid & 31;
  float xd[32];
  #pragma unroll
  for (int d = 0; d < 32; d++) xd[d] = S[row][hh * 32 + d];
  cf Xo[17];
  rdft32(xd, Xo);
  const size_t colbase = ((size_t)(b * 8 + hh) * 17) * 4096 + n0 + row;
  #pragma unroll
  for (int fd = 0; fd < 17; fd++)
    dst[colbase + (size_t)fd * 4096] = Xo[fd];
}

// ---------------------------------------------------------------------------
// Radix-8 DIT FFT, 4096 complex points, LDS swizzled (verified r0-3,7-9).
// Split into stages 0..2 (LDS) + last-stage variants that deliver directly
// to registers / global. Last stage (q=512): butterfly t covers positions
// t+512l; owner thread = t mod 256 = tid, register = r+2l  (mapping proof:
// spec[tid+256m] <-> out[m], m = r+2l).
// ---------------------------------------------------------------------------
#define FFT_LDS 4376   // swz(4095) = 4372

__device__ inline int swz(int i) { return i + (i >> 4) + (i >> 8) + (i >> 9); }
__device__ inline int digrev8(int n) {
  return ((n & 7) << 9) | (((n >> 3) & 7) << 6) | (((n >> 6) & 7) << 3) | ((n >> 9) & 7);
}

// DFT8 on x[0..7] (verified block), results into F[0..7]
template<int SIGN>
__device__ inline void dft8(const cf* x, cf* F) {
  const float C = 0.70710678118654752f;
  const float sg = (float)SIGN;
  cf u0 = cadd(x[0], x[4]), v0 = csub(x[0], x[4]);
  cf u1 = cadd(x[1], x[5]), v1 = csub(x[1], x[5]);
  cf u2 = cadd(x[2], x[6]), v2 = csub(x[2], x[6]);
  cf u3 = cadd(x[3], x[7]), v3 = csub(x[3], x[7]);
  cf w1v = make_float2(C * (v1.x - sg * v1.y), C * (v1.y + sg * v1.x));
  cf w2v = make_float2(-sg * v2.y, sg * v2.x);
  cf w3v = make_float2(C * (-v3.x - sg * v3.y), C * (sg * v3.x - v3.y));
  cf e0 = cadd(u0, u2), e1 = csub(u0, u2);
  cf o0 = cadd(u1, u3), o1 = csub(u1, u3);
  F[0] = cadd(e0, o0); F[4] = csub(e0, o0);
  F[2] = make_float2(e1.x - sg * o1.y, e1.y + sg * o1.x);
  F[6] = make_float2(e1.x + sg * o1.y, e1.y - sg * o1.x);
  cf e0b = cadd(v0, w2v), e1b = csub(v0, w2v);
  cf o0b = cadd(w1v, w3v), o1b = csub(w1v, w3v);
  F[1] = cadd(e0b, o0b); F[5] = csub(e0b, o0b);
  F[3] = make_float2(e1b.x - sg * o1b.y, e1b.y + sg * o1b.x);
  F[7] = make_float2(e1b.x + sg * o1b.y, e1b.y - sg * o1b.x);
}

// twiddle x[1..7] by w^l, w = e^{sg*2pi i * j / (8q)} (verified chain form)
template<int SIGN>
__device__ inline void twiddle8(cf* x, int j, int q8) {
  const float sg = (float)SIGN;
  float a = sg * 6.283185307179586f * (float)j / (float)q8;
  float sn, cs;
  __sincosf(a, &sn, &cs);
  cf w1 = make_float2(cs, sn);
  cf w = w1;
  #pragma unroll
  for (int l = 1; l < 8; l++) {
    x[l] = cmul(x[l], w);
    if (l < 7) w = cmul(w, w1);
  }
}

template<int SIGN>   // stages q=1,8,64 (s=0..2) in LDS
__device__ inline void fft8_stages3(cf* X, int tid)
{
  #pragma unroll
  for (int s = 0; s < 3; s++) {
    const int q = 1 << (3 * s);                  // 1, 8, 64
    __syncthreads();
    #pragma unroll
    for (int r = 0; r < 2; r++) {
      int t = tid + r * 256;
      int j = t & (q - 1);
      int base = ((t >> (3 * s)) << (3 * s + 3)) + j;
      cf x[8];
      #pragma unroll
      for (int l = 0; l < 8; l++) x[l] = X[swz(base + l * q)];
      if (s > 0) twiddle8<SIGN>(x, j, 8 * q);
      cf F[8];
      dft8<SIGN>(x, F);
      #pragma unroll
      for (int l = 0; l < 8; l++) X[swz(base + l * q)] = F[l];
    }
  }
}

// last stage (q=512): deliver spectrum to regs, out[m] = spec[tid + 256*m]
template<int SIGN>
__device__ inline void fft8_last_toreg(cf* X, int tid, cf* out)
{
  __syncthreads();
  #pragma unroll
  for (int r = 0; r < 2; r++) {
    int t = tid + r * 256;                       // j = t, base = t
    cf x[8];
    #pragma unroll
    for (int l = 0; l < 8; l++) x[l] = X[swz(t + l * 512)];
    twiddle8<SIGN>(x, t, 4096);
    cf F[8];
    dft8<SIGN>(x, F);
    #pragma unroll
    for (int l = 0; l < 8; l++) out[r + 2 * l] = F[l];
  }
}

// last stage, inverse path: store directly to global (coalesced per l)
template<int SIGN>
__device__ inline void fft8_last_toglobal(cf* X, int tid, cf* dst)
{
  __syncthreads();
  #pragma unroll
  for (int r = 0; r < 2; r++) {
    int t = tid + r * 256;
    cf x[8];
    #pragma unroll
    for (int l = 0; l < 8; l++) x[l] = X[swz(t + l * 512)];
    twiddle8<SIGN>(x, t, 4096);
    cf F[8];
    dft8<SIGN>(x, F);
    #pragma unroll
    for (int l = 0; l < 8; l++) dst[t + l * 512] = F[l];
  }
}

// ---------------------------------------------------------------------------
// K2: per-column seq conv. FFT tails deliver straight to registers; the
// inverse tail stores straight to global. Saves 3 LDS passes + 2 barriers.
// ---------------------------------------------------------------------------
__global__ __launch_bounds__(256) void seqconv(
    cf* __restrict__ Qd, const cf* __restrict__ Kd)
{
  __shared__ cf X[FFT_LDS];
  const size_t cb = (size_t)blockIdx.x * 4096;
  const int tid = threadIdx.x;

  #pragma unroll
  for (int i = 0; i < 16; i++) {
    int n = tid + i * 256;
    X[swz(digrev8(n))] = Qd[cb + n];
  }
  fft8_stages3<-1>(X, tid);
  cf qs[16];
  fft8_last_toreg<-1>(X, tid, qs);
  __syncthreads();                    // LDS reads done -> safe to overwrite

  #pragma unroll
  for (int i = 0; i < 16; i++) {
    int n = tid + i * 256;
    X[swz(digrev8(n))] = Kd[cb + n];
  }
  fft8_stages3<-1>(X, tid);
  cf fr[16];
  fft8_last_toreg<-1>(X, tid, fr);

  const float inv = 1.0f / 4096.0f;
  #pragma unroll
  for (int i = 0; i < 16; i++) {
    cf p = cmul(qs[i], fr[i]);
    qs[i] = make_float2(p.x * inv, p.y * inv);
  }
  __syncthreads();                    // LDS reads done -> safe to overwrite

  #pragma unroll
  for (int i = 0; i < 16; i++) {
    int f = tid + i * 256;
    X[swz(digrev8(f))] = qs[i];
  }
  fft8_stages3<+1>(X, tid);
  fft8_last_toglobal<+1>(X, tid, Qd + cb);
}

// ---------------------------------------------------------------------------
// K3: per-(n,h) irDFT-32 + softmax(d) + value gate + residual + LayerNorm.
// ---------------------------------------------------------------------------
__global__ __launch_bounds__(256) void finalize_kernel(
    const cf* __restrict__ Cd, const float* __restrict__ VL,
    const float* __restrict__ vin, const float* __restrict__ gamma,
    const float* __restrict__ beta, float* __restrict__ out)
{
  __shared__ cf Cs[136][33];
  __shared__ float gs[256], bs[256];
  const int n0 = blockIdx.x * 32;
  const int b = blockIdx.y;
  const int tid = threadIdx.x;
  gs[tid] = gamma[tid];
  bs[tid] = beta[tid];
  #pragma unroll
  for (int i = 0; i < 17; i++) {
    int lin = tid + i * 256;          // 0..4351 = 136 cols x 32 n
    int col = lin >> 5, nl = lin & 31;
    Cs[col][nl] = Cd[((size_t)b * 136 + col) * 4096 + n0 + nl];
  }
  __syncthreads();

  const int h = tid & 7, row = tid >> 3;
  const int n = n0 + row;

  cf Xs[17];
  #pragma unroll
  for (int fd = 0; fd < 17; fd++) Xs[fd] = Cs[h * 17 + fd][row];

  float att[32];
  irdft32(Xs, att);

  float mx = att[0];
  #pragma unroll
  for (int d = 1; d < 32; d++) mx = fmaxf(mx, att[d]);
  float ssum = 0.f;
  #pragma unroll
  for (int d = 0; d < 32; d++) { att[d] = __expf(att[d] - mx); ssum += att[d]; }
  const float rs = 1.0f / ssum;

  const size_t base = ((size_t)b * 4096 + n) * 256 + h * 32;
  float o[32];
  float s1 = 0.f, s2 = 0.f;
  #pragma unroll
  for (int i = 0; i < 8; i++) {
    float4 vl = *(const float4*)(VL + base + i * 4);
    float4 vi = *(const float4*)(vin + base + i * 4);
    float o0 = vl.x * (att[i * 4 + 0] * rs) + vi.x;
    float o1 = vl.y * (att[i * 4 + 1] * rs) + vi.y;
    float o2 = vl.z * (att[i * 4 + 2] * rs) + vi.z;
    float o3 = vl.w * (att[i * 4 + 3] * rs) + vi.w;
    o[i * 4 + 0] = o0; o[i * 4 + 1] = o1; o[i * 4 + 2] = o2; o[i * 4 + 3] = o3;
    s1 += o0 + o1 + o2 + o3;
    s2 += o0 * o0 + o1 * o1 + o2 * o2 + o3 * o3;
  }
  #pragma unroll
  for (int off = 1; off < 8; off <<= 1) {
    s1 += __shfl_xor(s1, off, 64);
    s2 += __shfl_xor(s2, off, 64);
  }
  const float mu = s1 * (1.0f / 256.0f);
  const float var = s2 * (1.0f / 256.0f) - mu * mu;
  const float rstd = rsqrtf(var + 1e-5f);
  #pragma unroll
  for (int i = 0; i < 8; i++) {
    float4 ov;
    ov.x = (o[i * 4 + 0] - mu) * rstd * gs[h * 32 + i * 4 + 0] + bs[h * 32 + i * 4 + 0];
    ov.y = (o[i * 4 + 1] - mu) * rstd * gs[h * 32 + i * 4 + 1] + bs[h * 32 + i * 4 + 1];
    ov.z = (o[i * 4 + 2] - mu) * rstd * gs[h * 32 + i * 4 + 2] + bs[h * 32 + i * 4 + 2];
    ov.w = (o[i * 4 + 3] - mu) * rstd * gs[h * 32 + i * 4 + 3] + bs[h * 32 + i * 4 + 3];
    *(float4*)(out + base + i * 4) = ov;
  }
}

// ---------------------------------------------------------------------------
extern "C" void kernel_launch(void* const* d_in, const int* in_sizes, int n_in,
                              void* d_out, int out_size, void* d_ws, size_t ws_size,
                              hipStream_t stream)
{
  const float* q  = (const float*)d_in[0];
  const float* k  = (const float*)d_in[1];
  const float* v  = (const float*)d_in[2];
  const float* Wq = (const float*)d_in[3];
  const float* bq = (const float*)d_in[4];
  const float* Wk = (const float*)d_in[5];
  const float* bk = (const float*)d_in[6];
  const float* Wv = (const float*)d_in[7];
  const float* bv = (const float*)d_in[8];
  const float* ln_gamma = (const float*)d_in[9];
  const float* ln_beta  = (const float*)d_in[10];
  float* out = (float*)d_out;

  float* ws = (float*)d_ws;
  float* QLm = ws;
  cf* Kd = (cf*)ws;
  float* KLm = ws + (size_t)8912896;
  float* VL  = ws + (size_t)17301504;
  cf* Qd = (cf*)(ws + (size_t)25690112);
  unsigned short* Whi = (unsigned short*)(ws + (size_t)34603008);
  unsigned short* Wlo = Whi + (size_t)3 * 65536;

  wconv<<<96, 256, 0, stream>>>(Wq, Wk, Wv, Whi, Wlo);

  gemm_proj<<<dim3(512, 1, 3), 256, 0, stream>>>(q, bq, k, bk, v, bv,
                                                 Whi, Wlo, QLm, KLm, VL);

  // ordered: dfft-Q reads QLm before dfft-K's output (Kd) overwrites it
  dfft<<<dim3(128, 8), 256, 0, stream>>>(QLm, Qd);
  dfft<<<dim3(128, 8), 256, 0, stream>>>(KLm, Kd);

  seqconv<<<1088, 256, 0, stream>>>(Qd, Kd);

  finalize_kernel<<<dim3(128, 8), 256, 0, stream>>>(Qd, VL, v, ln_gamma,
                                                    ln_beta, out);
}